// Round 7
// baseline (1089.100 us; speedup 1.0000x reference)
//
#include <hip/hip_runtime.h>
#include <hip/hip_cooperative_groups.h>

namespace cg = cooperative_groups;

#define N_NODES  200000
#define N_CHILD  32
#define N_LAYERS 8
#define CHUNK    40000   // floats per LDS chunk; 5*40000 = 200000 exactly
#define NCHUNK   5
#define NB       256     // 1 block per CU (LDS-bound anyway)
#define NPB      782     // ceil(200000/256) nodes per block
#define BT       1000    // 10000 float4 staged as exactly 10 per thread
#define PFN      10      // float4 prefetch regs per thread

// Fused cooperative LDS-sweep, software-pipelined:
//  - next chunk prefetched into registers while probing current chunk
//  - probes: sub+cmp+cndmask to a zero-slot (lds[40000]=0), batched 16-wide
//  - next layer's child indices prefetched before grid.sync()
__global__ __launch_bounds__(BT) void fused_kernel(
    const float* __restrict__ X,
    const float* __restrict__ wptr,
    const int*   __restrict__ child_idx,   // [N_LAYERS][N_NODES][N_CHILD]
    const int*   __restrict__ fun_ids,     // [N_LAYERS][N_NODES]
    float*       __restrict__ bufA,
    float*       __restrict__ bufB,
    float*       __restrict__ out)
{
    cg::grid_group grid = cg::this_grid();
    __shared__ __align__(16) float lds[CHUNK + 4];
    const int  tid    = threadIdx.x;
    const int  node   = blockIdx.x * NPB + tid;
    const bool active = (tid < NPB) && (node < N_NODES);
    if (tid == 0) lds[CHUNK] = 0.0f;            // zero slot for invalid probes
    const float w0 = wptr[0];

    // layer-0 indices -> registers
    int idx[N_CHILD];
    int fid = 3;
    if (active) {
        const int4* ci = (const int4*)(child_idx + (size_t)node * N_CHILD);
        #pragma unroll
        for (int j = 0; j < N_CHILD / 4; ++j) {
            int4 c = ci[j];
            idx[4*j+0] = c.x; idx[4*j+1] = c.y;
            idx[4*j+2] = c.z; idx[4*j+3] = c.w;
        }
        fid = fun_ids[node];
    } else {
        #pragma unroll
        for (int j = 0; j < N_CHILD; ++j) idx[j] = 0;
    }

    const float* cur = X;
    for (int l = 0; l < N_LAYERS; ++l) {
        float* nxt = (l == N_LAYERS - 1) ? out : ((l & 1) ? bufB : bufA);
        const float4* __restrict__ src4 = (const float4*)cur;

        float4 pf[PFN];
        #pragma unroll
        for (int k = 0; k < PFN; ++k) pf[k] = src4[tid + k * BT];   // chunk 0

        float s = 0.0f;
        #pragma unroll 1
        for (int c = 0; c < NCHUNK; ++c) {
            __syncthreads();   // LDS free (previous chunk's probes done)
            {
                float4* dst4 = (float4*)lds;
                #pragma unroll
                for (int k = 0; k < PFN; ++k) dst4[tid + k * BT] = pf[k];
            }
            if (c < NCHUNK - 1) {
                const int b4 = (c + 1) * (CHUNK / 4);
                #pragma unroll
                for (int k = 0; k < PFN; ++k) pf[k] = src4[b4 + tid + k * BT];
            }
            __syncthreads();   // chunk staged; prefetch of c+1 in flight
            if (active) {
                const unsigned cbase = (unsigned)(c * CHUNK);
                #pragma unroll
                for (int h = 0; h < 2; ++h) {
                    unsigned off[16];
                    float    v[16];
                    #pragma unroll
                    for (int j = 0; j < 16; ++j) {
                        unsigned o = (unsigned)idx[h*16 + j] - cbase;
                        off[j] = (o < (unsigned)CHUNK) ? o : (unsigned)CHUNK;
                    }
                    #pragma unroll
                    for (int j = 0; j < 16; ++j) v[j] = lds[off[j]];
                    #pragma unroll
                    for (int j = 0; j < 16; ++j) s += v[j];
                }
            }
        }

        if (active) {
            float x = w0 * s;
            float y;
            if (fid == 0)      y = tanhf(x);
            else if (fid == 1) y = 1.0f / (1.0f + __expf(-x));  // safe at +-inf
            else if (fid == 2) y = fmaxf(x, 0.0f);
            else               y = x;
            nxt[node] = y;
        }

        if (l < N_LAYERS - 1 && active) {   // prefetch next layer's indices
            const int4* ci = (const int4*)(child_idx
                               + ((size_t)(l + 1) * N_NODES + node) * N_CHILD);
            #pragma unroll
            for (int j = 0; j < N_CHILD / 4; ++j) {
                int4 c = ci[j];
                idx[4*j+0] = c.x; idx[4*j+1] = c.y;
                idx[4*j+2] = c.z; idx[4*j+3] = c.w;
            }
            fid = fun_ids[(size_t)(l + 1) * N_NODES + node];
        }
        grid.sync();
        cur = nxt;
    }
}

extern "C" void kernel_launch(void* const* d_in, const int* in_sizes, int n_in,
                              void* d_out, int out_size, void* d_ws, size_t ws_size,
                              hipStream_t stream) {
    const float* X         = (const float*)d_in[0];
    const float* w         = (const float*)d_in[1];
    const int*   child_idx = (const int*)d_in[2];
    const int*   fun_ids   = (const int*)d_in[3];
    float*       out       = (float*)d_out;
    float*       bufA      = (float*)d_ws;                  // 800 KB ping
    float*       bufB      = (float*)d_ws + 200704;         // pong

    void* args[] = { (void*)&X, (void*)&w, (void*)&child_idx, (void*)&fun_ids,
                     (void*)&bufA, (void*)&bufB, (void*)&out };
    hipLaunchCooperativeKernel((const void*)fused_kernel,
                               dim3(NB), dim3(BT), args, 0, stream);
}

// Round 8
// 661.600 us; speedup vs baseline: 1.6462x; 1.6462x over previous
//
#include <hip/hip_runtime.h>

#define N_NODES  200000
#define N_CHILD  32
#define N_LAYERS 8
#define CHUNK    79872      // bf16 elems/chunk = 159744 B = 9984 16B-units = 832*12
#define NCHUNK   3          // 3*79872 = 239616 >= 200000
#define NB       256        // 1 block per CU
#define NPB      782        // ceil(200000/256)
#define BT       832        // 13 waves; 782/832 = 94% lanes active
#define PFN      12         // 16B units staged per thread per chunk
#define NUNIT    25000      // 200000 bf16 = 400000 B = 25000 16B units

// bf16 LDS sweep: table halved to 400 KB -> 3 chunks (96 probes/thread vs 160),
// 16-wide batched branchless probes to a zero-slot, register prefetch of the
// next chunk issued after the staging barrier (overlaps probe phase).
// 8 plain dispatches: cooperative fusion proved toxic (grid.sync acquire
// invalidates L2 -> 907 MB/dispatch refetch, R7).

__device__ __forceinline__ unsigned short f2bf(float f) {
    unsigned u = __float_as_uint(f);
    u += 0x7FFFu + ((u >> 16) & 1u);          // round-to-nearest-even
    return (unsigned short)(u >> 16);
}

__global__ __launch_bounds__(256) void convert_kernel(
    const float* __restrict__ X, unsigned short* __restrict__ T)
{
    int i = blockIdx.x * 256 + threadIdx.x;
    if (i < N_NODES) T[i] = f2bf(X[i]);
}

__global__ __launch_bounds__(BT) void layer_kernel(
    const uint4*    __restrict__ tab4,      // bf16 value table as 16B units
    unsigned short* __restrict__ out_bf,    // bf16 output table (intermediate layers)
    float*          __restrict__ out_f32,   // f32 output (last layer only, else null)
    const int*      __restrict__ child_idx, // [N_NODES][N_CHILD] this layer
    const int*      __restrict__ fun_ids,   // [N_NODES] this layer
    const float*    __restrict__ wptr)
{
    __shared__ __align__(16) unsigned short lds[CHUNK + 8];
    const int  tid    = threadIdx.x;
    const int  node   = blockIdx.x * NPB + tid;
    const bool active = (tid < NPB) && (node < N_NODES);
    if (tid == 0) lds[CHUNK] = 0;             // zero slot for out-of-chunk probes
    const float w0 = wptr[0];

    int idx[N_CHILD];
    int fid = 3;
    if (active) {
        const int4* ci = (const int4*)(child_idx + (size_t)node * N_CHILD);
        #pragma unroll
        for (int j = 0; j < N_CHILD / 4; ++j) {
            int4 c = ci[j];
            idx[4*j+0] = c.x; idx[4*j+1] = c.y;
            idx[4*j+2] = c.z; idx[4*j+3] = c.w;
        }
        fid = fun_ids[node];
    } else {
        #pragma unroll
        for (int j = 0; j < N_CHILD; ++j) idx[j] = 0;
    }

    // prefetch chunk 0 into registers (clamped: OOB units re-read last unit)
    uint4 pf[PFN];
    #pragma unroll
    for (int k = 0; k < PFN; ++k) pf[k] = tab4[min(tid + k * BT, NUNIT - 1)];

    float s = 0.0f;
    #pragma unroll 1
    for (int c = 0; c < NCHUNK; ++c) {
        __syncthreads();                      // previous chunk's probes done
        {
            uint4* dst = (uint4*)lds;
            #pragma unroll
            for (int k = 0; k < PFN; ++k) dst[tid + k * BT] = pf[k];
        }
        __syncthreads();                      // chunk c staged
        if (c + 1 < NCHUNK) {                 // prefetch c+1 DURING probes
            const int b = (c + 1) * (CHUNK / 8);
            #pragma unroll
            for (int k = 0; k < PFN; ++k)
                pf[k] = tab4[min(b + tid + k * BT, NUNIT - 1)];
        }
        const unsigned cbase = (unsigned)(c * CHUNK);
        #pragma unroll
        for (int h = 0; h < N_CHILD / 16; ++h) {
            unsigned off[16];
            #pragma unroll
            for (int j = 0; j < 16; ++j) {
                unsigned o = (unsigned)idx[h*16 + j] - cbase;
                off[j] = (o < (unsigned)CHUNK) ? o : (unsigned)CHUNK;  // miss -> zero slot
            }
            float v[16];
            #pragma unroll
            for (int j = 0; j < 16; ++j)
                v[j] = __uint_as_float((unsigned)lds[off[j]] << 16);   // exact bf16->f32
            #pragma unroll
            for (int j = 0; j < 16; ++j) s += v[j];
        }
    }

    if (active) {
        float x = w0 * s;
        float y;
        if (fid == 0)      y = tanhf(x);
        else if (fid == 1) y = 1.0f / (1.0f + __expf(-x));  // safe at +-inf
        else if (fid == 2) y = fmaxf(x, 0.0f);
        else               y = x;
        if (out_f32) out_f32[node] = y;
        else         out_bf[node] = f2bf(y);
    }
}

extern "C" void kernel_launch(void* const* d_in, const int* in_sizes, int n_in,
                              void* d_out, int out_size, void* d_ws, size_t ws_size,
                              hipStream_t stream) {
    const float* X         = (const float*)d_in[0];
    const float* w         = (const float*)d_in[1];
    const int*   child_idx = (const int*)d_in[2];
    const int*   fun_ids   = (const int*)d_in[3];
    float*       out       = (float*)d_out;

    unsigned short* bufA = (unsigned short*)d_ws;                       // 401408 B slot
    unsigned short* bufB = (unsigned short*)((char*)d_ws + 401408);

    convert_kernel<<<(N_NODES + 255) / 256, 256, 0, stream>>>(X, bufA);

    for (int l = 0; l < N_LAYERS; ++l) {
        unsigned short* in_t  = (l & 1) ? bufB : bufA;
        unsigned short* out_t = (l & 1) ? bufA : bufB;
        bool last = (l == N_LAYERS - 1);
        layer_kernel<<<NB, BT, 0, stream>>>(
            (const uint4*)in_t,
            last ? (unsigned short*)nullptr : out_t,
            last ? out : (float*)nullptr,
            child_idx + (size_t)l * N_NODES * N_CHILD,
            fun_ids   + (size_t)l * N_NODES,
            w);
    }
}